// Round 26
// baseline (72.480 us; speedup 1.0000x reference)
//
#include <hip/hip_runtime.h>
#include <math.h>

// Problem constants
#define MROWS 8192   // B*S
#define BATCH 4
#define SEQ   2048
#define CDIM  256
#define HEADS 8
#define DHEAD 32
#define FDIM  512
#define QKVN  768    // 3*C

typedef __attribute__((ext_vector_type(8))) short bf16x8;
typedef __attribute__((ext_vector_type(4))) float f32x4;

__device__ __forceinline__ unsigned pk_bf16(float a, float b) {
  unsigned r;
  asm("v_cvt_pk_bf16_f32 %0, %1, %2" : "=v"(r) : "v"(a), "v"(b));
  return r;
}
__device__ __forceinline__ float bf2f(short s) {
  unsigned u = ((unsigned)(unsigned short)s) << 16;
  return __builtin_bit_cast(float, u);
}
__device__ __forceinline__ float bflo(unsigned w) {
  return __builtin_bit_cast(float, w << 16);
}
__device__ __forceinline__ float bfhi(unsigned w) {
  return __builtin_bit_cast(float, w & 0xffff0000u);
}
__device__ __forceinline__ short f2bf(float f) {
  unsigned u = __builtin_bit_cast(unsigned, f);
  u = (u + 0x7FFFu + ((u >> 16) & 1u)) >> 16;   // RNE
  return (short)u;
}
__device__ __forceinline__ float fexp2(float x) {
#if __has_builtin(__builtin_amdgcn_exp2f)
  return __builtin_amdgcn_exp2f(x);
#else
  return exp2f(x);
#endif
}
__device__ __forceinline__ void gl16(const void* g, void* l) {
  __builtin_amdgcn_global_load_lds(
      (const __attribute__((address_space(1))) void*)g,
      (__attribute__((address_space(3))) void*)l, 16, 0, 0);
}
__device__ __forceinline__ float gelu_tanh(float v) {
  const float u = v * (0.7978845608f + 0.0356774081f * v * v);
  const float t = fexp2(u * 2.885390082f);   // e^{2u}
  return v * t / (t + 1.0f);                 // 0.5v(1+tanh u)
}

// ---------------------------------------------------------------------------
// Fused fp32 -> bf16 casts: pillar + 4 weight tensors, exact block ranges.
// ---------------------------------------------------------------------------
__global__ __launch_bounds__(256) void cast_all_k(
    const float* __restrict__ pillar, short* __restrict__ pb,
    const float* __restrict__ wq, short* __restrict__ wqb,
    const float* __restrict__ wo, short* __restrict__ wob,
    const float* __restrict__ w1, short* __restrict__ w1b,
    const float* __restrict__ w2, short* __restrict__ w2b)
{
  const int i = blockIdx.x * 256 + threadIdx.x;
  const float* s; short* d; int off;
  if (i < 524288)      { s = pillar; d = pb;  off = i; }
  else if (i < 573440) { s = wq;     d = wqb; off = i - 524288; }
  else if (i < 589824) { s = wo;     d = wob; off = i - 573440; }
  else if (i < 622592) { s = w1;     d = w1b; off = i - 589824; }
  else                 { s = w2;     d = w2b; off = i - 622592; }
  float4 v = reinterpret_cast<const float4*>(s)[off];
  uint2 o = { pk_bf16(v.x, v.y), pk_bf16(v.z, v.w) };
  *reinterpret_cast<uint2*>(d + off*4) = o;
}

// ---------------------------------------------------------------------------
// bf16 MFMA GEMM, 128x64 tile, BK=64, 512 threads (8 waves as 4m x 2n of
// 32x32 quadrants). gl16 staging (3 per thread), XOR-pre-swizzled source,
// linear LDS, double-buffered. Swapped MFMA: lane = m, regs = 4 consecutive
// n. NS = output row stride. VOUT: blocks with n0>=512 write the V-third of
// QKV transposed to vt[(b*8+h)*32+dv][s] (bf16) for gl16-direct V staging.
// ---------------------------------------------------------------------------
template<int K, bool BF16OUT, bool GELU, bool VOUT>
__global__ __launch_bounds__(512, 4) void gemm128_k(
    const short* __restrict__ A, const short* __restrict__ W,
    const float* __restrict__ bias, void* __restrict__ out,
    short* __restrict__ vt, int NS)
{
  __shared__ short AS[2][8192];   // [128][64] linear, swizzled content
  __shared__ short WS[2][4096];   // [64][64]
  const int tid = threadIdx.x;
  const int l   = tid & 63;
  const int w   = tid >> 6;       // 0..7
  const int m0 = blockIdx.x * 128;
  const int n0 = blockIdx.y * 64;
  const int wr = (w >> 1) * 32;   // 0,32,64,96
  const int wc = (w & 1) * 32;    // 0,32
  const int lr = l & 15;
  const int lg = l >> 4;

  f32x4 acc[2][2];
#pragma unroll
  for (int i = 0; i < 2; ++i)
#pragma unroll
    for (int j = 0; j < 2; ++j) acc[i][j] = (f32x4){0.f,0.f,0.f,0.f};

  auto stage = [&](int buf, int k0) {
#pragma unroll
    for (int i = 0; i < 2; ++i) {         // A: 1024 chunks, 2 per thread
      const int c = i*512 + tid;
      const int r = c >> 3;
      const int s = (c & 7) ^ (r & 7);    // pre-swizzled source chunk
      gl16(A + (size_t)(m0 + r)*K + k0 + s*8, &AS[buf][c*8]);
    }
    {                                      // W: 512 chunks, 1 per thread
      const int c = tid;
      const int r = c >> 3;
      const int s = (c & 7) ^ (r & 7);
      gl16(W + (size_t)(n0 + r)*K + k0 + s*8, &WS[buf][c*8]);
    }
  };

  stage(0, 0);
  const int NST = K / 64;
  for (int t = 0; t < NST; ++t) {
    const int buf = t & 1;
    __syncthreads();
    if (t + 1 < NST) stage(buf ^ 1, (t+1)*64);
#pragma unroll
    for (int ks = 0; ks < 2; ++ks) {
      const int sl = ((ks*4 + lg) ^ (lr & 7)) << 3;
      bf16x8 a[2], b[2];
#pragma unroll
      for (int mi = 0; mi < 2; ++mi)
        a[mi] = *reinterpret_cast<const bf16x8*>(&AS[buf][(wr + mi*16 + lr)*64 + sl]);
#pragma unroll
      for (int nj = 0; nj < 2; ++nj)
        b[nj] = *reinterpret_cast<const bf16x8*>(&WS[buf][(wc + nj*16 + lr)*64 + sl]);
#pragma unroll
      for (int mi = 0; mi < 2; ++mi)
#pragma unroll
        for (int nj = 0; nj < 2; ++nj)
          acc[mi][nj] = __builtin_amdgcn_mfma_f32_16x16x32_bf16(b[nj], a[mi], acc[mi][nj], 0, 0, 0);
    }
  }

#pragma unroll
  for (int mi = 0; mi < 2; ++mi) {
    const size_t m = m0 + wr + mi*16 + lr;
#pragma unroll
    for (int nj = 0; nj < 2; ++nj) {
      const int nf = n0 + wc + nj*16 + lg*4;    // full logical column
      float4 bs = *reinterpret_cast<const float4*>(&bias[nf]);
      f32x4 v = acc[mi][nj];
      float v0 = v[0]+bs.x, v1 = v[1]+bs.y, v2 = v[2]+bs.z, v3 = v[3]+bs.w;
      if (GELU) { v0 = gelu_tanh(v0); v1 = gelu_tanh(v1); v2 = gelu_tanh(v2); v3 = gelu_tanh(v3); }
      if (VOUT && n0 >= 512) {
        // V-third -> transposed vt[(b*8+h)*32+dv][s]
        const int nl = nf - 512;
        const int hh = nl >> 5, dvb = nl & 31;
        const int bb = (int)(m >> 11), ss = (int)(m & 2047);
        short* vp = vt + ((size_t)((bb*8 + hh)*32 + dvb))*2048 + ss;
        vp[0] = f2bf(v0); vp[2048] = f2bf(v1); vp[4096] = f2bf(v2); vp[6144] = f2bf(v3);
      } else if (BF16OUT) {
        uint2 p = { pk_bf16(v0, v1), pk_bf16(v2, v3) };
        *reinterpret_cast<uint2*>((short*)out + m*NS + nf) = p;
      } else {
        float4 p = { v0, v1, v2, v3 };
        *reinterpret_cast<float4*>((float*)out + m*NS + nf) = p;
      }
    }
  }
}

// ---------------------------------------------------------------------------
// MFMA flash attention v11: 2 Q-frags/wave, key-split 8 waves, 3-deep
// counted-vmcnt gl16 pipeline, setprio around compute, single-pass merge.
// ---------------------------------------------------------------------------
__global__ __launch_bounds__(512, 4) void attn_mfma_k(
    const short* __restrict__ qk, const short* __restrict__ vtg,
    short* __restrict__ attno)
{
  __shared__ short KS[2][3][2048];   // [stream][buf] 64 perm key rows x 32 d
  __shared__ short VS[2][3][2048];   // [stream][buf] 32 dv x 64 keys

  const int tid  = threadIdx.x;
  const int lane = tid & 63;
  const int wv   = tid >> 6;       // 0..7
  const int st   = wv >> 2;        // key stream 0/1
  const int qw   = wv & 3;         // q subtile (32 rows)
  const int bh   = blockIdx.y;
  const int b    = bh >> 3, h = bh & 7;
  const int q0   = blockIdx.x * 128 + qw * 32;

  const int lr = lane & 15;
  const int lg = lane >> 4;

  // Two Q fragments prescaled by 1/sqrt(D) * log2(e)  (qk row stride 512)
  bf16x8 qfa, qfb;
  {
    const float c = 0.25508134f;
    bf16x8 ra = *reinterpret_cast<const bf16x8*>(
        qk + (size_t)(b*SEQ + q0 + lr)*512 + h*DHEAD + lg*8);
    bf16x8 rb = *reinterpret_cast<const bf16x8*>(
        qk + (size_t)(b*SEQ + q0 + 16 + lr)*512 + h*DHEAD + lg*8);
#pragma unroll
    for (int j = 0; j < 8; ++j) {
      qfa[j] = f2bf(bf2f(ra[j]) * c);
      qfb[j] = f2bf(bf2f(rb[j]) * c);
    }
  }
  bf16x8 ones;
#pragma unroll
  for (int j = 0; j < 8; ++j) ones[j] = (short)0x3F80;  // bf16 1.0

  f32x4 oa0 = {0.f,0.f,0.f,0.f}, oa1 = {0.f,0.f,0.f,0.f};
  f32x4 ob0 = {0.f,0.f,0.f,0.f}, ob1 = {0.f,0.f,0.f,0.f};
  f32x4 la  = {0.f,0.f,0.f,0.f}, lb  = {0.f,0.f,0.f,0.f};

  // --- staging source precompute (per stream-thread; 1 K + 1 V chunk) ---
  const int t256 = tid & 255;
  const short* kSrc;
  {
    const int r = t256 >> 2, s = t256 & 3;
    const int rr = r & 31;
    const int key = ((rr >> 2) & 3)*8 + ((rr >> 4) & 1)*4 + (rr & 3) + (r & 32);
    const int slog = s ^ ((r >> 1) & 3);
    kSrc = qk + (size_t)(b*SEQ + st*1024 + key)*512 + 256 + h*DHEAD + slog*8;
  }
  const short* vSrc;
  {
    const int r = t256 >> 3, s = t256 & 7;
    const int slog = s ^ (r & 7);
    vSrc = vtg + ((size_t)(bh*32 + r))*2048 + st*1024 + slog*8;
  }

  // prologue: issue tiles 0 and 1 (2 gl16 per thread per tile)
  gl16(kSrc, &KS[st][0][t256*8]);
  gl16(vSrc, &VS[st][0][t256*8]);
  kSrc += 64*512; vSrc += 64;
  gl16(kSrc, &KS[st][1][t256*8]);
  gl16(vSrc, &VS[st][1][t256*8]);
  kSrc += 64*512; vSrc += 64;

  const int kxor = (lr >> 1) & 3;
  const int vxor = lr & 7;

  int buf = 0, nbuf = 2;           // buf = t%3 ; nbuf = (t+2)%3
  for (int t = 0; t < 16; ++t) {
    // own tile-t loads landed (in-order vmcnt: <=2 outstanding = t+1's)
    if (t < 15) asm volatile("s_waitcnt vmcnt(2)" ::: "memory");
    else        asm volatile("s_waitcnt vmcnt(0)" ::: "memory");
    __builtin_amdgcn_s_barrier();    // all waves' t-loads landed
    asm volatile("" ::: "memory");   // compiler fence (no LDS-read hoisting)

    if (t + 2 < 16) {                // overwrite buf (t-1)%3: reads done
      gl16(kSrc, &KS[st][nbuf][t256*8]);
      gl16(vSrc, &VS[st][nbuf][t256*8]);
      kSrc += 64*512; vSrc += 64;
    }

    __builtin_amdgcn_s_setprio(1);   // T5: favor compute-phase waves

#pragma unroll
    for (int half = 0; half < 2; ++half) {
      const int krow = (half*32 + lr)*32 + ((lg ^ kxor) << 3);
      bf16x8 kf0 = *reinterpret_cast<const bf16x8*>(&KS[st][buf][krow]);
      bf16x8 kf1 = *reinterpret_cast<const bf16x8*>(&KS[st][buf][krow + 512]);
      const int vcol = (((half*4 + lg) ^ vxor) << 3);
      bf16x8 vf0 = *reinterpret_cast<const bf16x8*>(&VS[st][buf][lr*64 + vcol]);
      bf16x8 vf1 = *reinterpret_cast<const bf16x8*>(&VS[st][buf][(lr+16)*64 + vcol]);
      f32x4 z = {0.f,0.f,0.f,0.f};

      // frag A (q rows q0+lr)
      {
        f32x4 s0 = __builtin_amdgcn_mfma_f32_16x16x32_bf16(kf0, qfa, z, 0, 0, 0);
        f32x4 s1 = __builtin_amdgcn_mfma_f32_16x16x32_bf16(kf1, qfa, z, 0, 0, 0);
        float p0 = fexp2(s0[0]), p1 = fexp2(s0[1]), p2 = fexp2(s0[2]), p3 = fexp2(s0[3]);
        float p4 = fexp2(s1[0]), p5 = fexp2(s1[1]), p6 = fexp2(s1[2]), p7 = fexp2(s1[3]);
        union { bf16x8 v; unsigned w[4]; } pfu;
        pfu.w[0] = pk_bf16(p0, p1); pfu.w[1] = pk_bf16(p2, p3);
        pfu.w[2] = pk_bf16(p4, p5); pfu.w[3] = pk_bf16(p6, p7);
        oa0 = __builtin_amdgcn_mfma_f32_16x16x32_bf16(vf0, pfu.v, oa0, 0, 0, 0);
        oa1 = __builtin_amdgcn_mfma_f32_16x16x32_bf16(vf1, pfu.v, oa1, 0, 0, 0);
        la  = __builtin_amdgcn_mfma_f32_16x16x32_bf16(ones, pfu.v, la, 0, 0, 0);
      }
      // frag B (q rows q0+16+lr)
      {
        f32x4 s0 = __builtin_amdgcn_mfma_f32_16x16x32_bf16(kf0, qfb, z, 0, 0, 0);
        f32x4 s1 = __builtin_amdgcn_mfma_f32_16x16x32_bf16(kf1, qfb, z, 0, 0, 0);
        float p0 = fexp2(s0[0]), p1 = fexp2(s0[1]), p2 = fexp2(s0[2]), p3 = fexp2(s0[3]);
        float p4 = fexp2(s1[0]), p5 = fexp2(s1[1]), p6 = fexp2(s1[2]), p7 = fexp2(s1[3]);
        union { bf16x8 v; unsigned w[4]; } pfu;
        pfu.w[0] = pk_bf16(p0, p1); pfu.w[1] = pk_bf16(p2, p3);
        pfu.w[2] = pk_bf16(p4, p5); pfu.w[3] = pk_bf16(p6, p7);
        ob0 = __builtin_amdgcn_mfma_f32_16x16x32_bf16(vf0, pfu.v, ob0, 0, 0, 0);
        ob1 = __builtin_amdgcn_mfma_f32_16x16x32_bf16(vf1, pfu.v, ob1, 0, 0, 0);
        lb  = __builtin_amdgcn_mfma_f32_16x16x32_bf16(ones, pfu.v, lb, 0, 0, 0);
      }
    }

    __builtin_amdgcn_s_setprio(0);

    buf = (buf == 2) ? 0 : buf + 1;
    nbuf = (nbuf == 2) ? 0 : nbuf + 1;
  }

  // single-pass merge of the two key streams: mg = [(qw*64+lane)*2+frag]*9
  // floats = 18,432B, entirely within KS (24,576B). Pure sums (max-free SM).
  float* mg = (float*)&KS[0][0][0];
  const int mia = ((qw*64 + lane)*2 + 0)*9;
  const int mib = ((qw*64 + lane)*2 + 1)*9;

  __syncthreads();                      // all tile-15 LDS reads done
  if (st == 1) {
    mg[mia+0]=oa0[0]; mg[mia+1]=oa0[1]; mg[mia+2]=oa0[2]; mg[mia+3]=oa0[3];
    mg[mia+4]=oa1[0]; mg[mia+5]=oa1[1]; mg[mia+6]=oa1[2]; mg[mia+7]=oa1[3];
    mg[mia+8]=la[0];
    mg[mib+0]=ob0[0]; mg[mib+1]=ob0[1]; mg[mib+2]=ob0[2]; mg[mib+3]=ob0[3];
    mg[mib+4]=ob1[0]; mg[mib+5]=ob1[1]; mg[mib+6]=ob1[2]; mg[mib+7]=ob1[3];
    mg[mib+8]=lb[0];
  }
  __syncthreads();
  if (st == 0) {
    {
      const float inv = 1.f / (la[0] + mg[mia+8]);
      float a0 = (oa0[0]+mg[mia+0])*inv, a1 = (oa0[1]+mg[mia+1])*inv;
      float a2 = (oa0[2]+mg[mia+2])*inv, a3 = (oa0[3]+mg[mia+3])*inv;
      float b0 = (oa1[0]+mg[mia+4])*inv, b1 = (oa1[1]+mg[mia+5])*inv;
      float b2 = (oa1[2]+mg[mia+6])*inv, b3 = (oa1[3]+mg[mia+7])*inv;
      short* op = attno + (size_t)(b*SEQ + q0 + lr)*CDIM + h*DHEAD;
      uint2 r0 = { pk_bf16(a0, a1), pk_bf16(a2, a3) };
      uint2 r1 = { pk_bf16(b0, b1), pk_bf16(b2, b3) };
      *reinterpret_cast<uint2*>(op + lg*4)      = r0;
      *reinterpret_cast<uint2*>(op + 16 + lg*4) = r1;
    }
    {
      const float inv = 1.f / (lb[0] + mg[mib+8]);
      float a0 = (ob0[0]+mg[mib+0])*inv, a1 = (ob0[1]+mg[mib+1])*inv;
      float a2 = (ob0[2]+mg[mib+2])*inv, a3 = (ob0[3]+mg[mib+3])*inv;
      float b0 = (ob1[0]+mg[mib+4])*inv, b1 = (ob1[1]+mg[mib+5])*inv;
      float b2 = (ob1[2]+mg[mib+6])*inv, b3 = (ob1[3]+mg[mib+7])*inv;
      short* op = attno + (size_t)(b*SEQ + q0 + 16 + lr)*CDIM + h*DHEAD;
      uint2 r0 = { pk_bf16(a0, a1), pk_bf16(a2, a3) };
      uint2 r1 = { pk_bf16(b0, b1), pk_bf16(b2, b3) };
      *reinterpret_cast<uint2*>(op + lg*4)      = r0;
      *reinterpret_cast<uint2*>(op + 16 + lg*4) = r1;
    }
  }
}

// ---------------------------------------------------------------------------
// Fused GEMM(N=256) + residual + LayerNorm, 16-row x 256-col tile per block
// (512 blocks = 2 blocks/CU for barrier-drain overlap). 8 waves, each owns
// 32 cols (2 n-frags); same gl16+swizzle dbuf staging skeleton as gemm128_k.
// Epilogue: residual add (bf16), row-reduce via shfl_xor over lg + LDS
// partials over the 8 waves, normalize, write bf16 or fp32.
// ---------------------------------------------------------------------------
template<int K, bool F32OUT>
__global__ __launch_bounds__(512, 4) void gemmln_k(
    const short* __restrict__ A, const short* __restrict__ W,
    const float* __restrict__ bias, const short* __restrict__ resid,
    const float* __restrict__ g, const float* __restrict__ bta,
    float* __restrict__ outf, short* __restrict__ outb)
{
  __shared__ short AS[2][1024];    // [16][64]
  __shared__ short WS[2][16384];   // [256][64]
  __shared__ float P[16][8][2];    // per-(row, wave) partial sum/sumsq
  const int tid = threadIdx.x;
  const int l   = tid & 63;
  const int wv  = tid >> 6;        // 0..7: cols wv*32..+31
  const int m0  = blockIdx.x * 16;
  const int lr  = l & 15;
  const int lg  = l >> 4;

  f32x4 acc[2];
#pragma unroll
  for (int j = 0; j < 2; ++j) acc[j] = (f32x4){0.f,0.f,0.f,0.f};

  auto stage = [&](int buf, int k0) {
    if (tid < 128) {                     // A: 16 rows x 8 chunks
      const int r = tid >> 3;
      const int s = (tid & 7) ^ (r & 7);
      gl16(A + (size_t)(m0 + r)*K + k0 + s*8, &AS[buf][tid*8]);
    }
#pragma unroll
    for (int i = 0; i < 4; ++i) {        // W: 256 rows x 8 chunks = 2048
      const int c = i*512 + tid;
      const int r = c >> 3;
      const int s = (c & 7) ^ (r & 7);
      gl16(W + (size_t)r*K + k0 + s*8, &WS[buf][c*8]);
    }
  };

  stage(0, 0);
  const int NST = K / 64;
  for (int t = 0; t < NST; ++t) {
    const int buf = t & 1;
    __syncthreads();
    if (t + 1 < NST) stage(buf ^ 1, (t+1)*64);
#pragma unroll
    for (int ks = 0; ks < 2; ++ks) {
      const int sl = ((ks*4 + lg) ^ (lr & 7)) << 3;
      bf16x8 a = *reinterpret_cast<const bf16x8*>(&AS[buf][lr*64 + sl]);
#pragma unroll
      for (int nj = 0; nj < 2; ++nj) {
        bf16x8 b = *reinterpret_cast<const bf16x8*>(&WS[buf][(wv*32 + nj*16 + lr)*64 + sl]);
        acc[nj] = __builtin_amdgcn_mfma_f32_16x16x32_bf16(b, a, acc[nj], 0, 0, 0);
      }
    }
  }

  // epilogue: bias + residual, row stats, LN
  const int m = m0 + lr;
  float vals[8];
  float s = 0.f, sq = 0.f;
#pragma unroll
  for (int nj = 0; nj < 2; ++nj) {
    const int col = wv*32 + nj*16 + lg*4;
    float4 bs = *reinterpret_cast<const float4*>(&bias[col]);
    uint2 rv = *reinterpret_cast<const uint2*>(&resid[(size_t)m*CDIM + col]);
    float v0 = acc[nj][0] + bs.x + bflo(rv.x);
    float v1 = acc[nj][1] + bs.y + bfhi(rv.x);
    float v2 = acc[nj][2] + bs.z + bflo(rv.y);
    float v3 = acc[nj][3] + bs.w + bfhi(rv.y);
    vals[nj*4+0]=v0; vals[nj*4+1]=v1; vals[nj*4+2]=v2; vals[nj*4+3]=v3;
    s += (v0+v1)+(v2+v3);
    sq += (v0*v0+v1*v1)+(v2*v2+v3*v3);
  }
  // reduce across the 4 lg-lanes (same row, 32 cols of this wave)
  s  += __shfl_xor(s, 16);  s  += __shfl_xor(s, 32);
  sq += __shfl_xor(sq, 16); sq += __shfl_xor(sq, 32);
  if (lg == 0) { P[lr][wv][0] = s; P[lr][wv][1] = sq; }
  __syncthreads();
  float S = 0.f, SQ = 0.f;
#pragma unroll
  for (int w8 = 0; w8 < 8; ++w8) { S += P[lr][w8][0]; SQ += P[lr][w8][1]; }
  const float mean = S * (1.f/CDIM);
  const float var  = SQ * (1.f/CDIM) - mean*mean;
  const float rstd = rsqrtf(var + 1e-5f);
#pragma unroll
  for (int nj = 0; nj < 2; ++nj) {
    const int col = wv*32 + nj*16 + lg*4;
    float4 gv = *reinterpret_cast<const float4*>(&g[col]);
    float4 bv = *reinterpret_cast<const float4*>(&bta[col]);
    float r0 = (vals[nj*4+0]-mean)*rstd*gv.x + bv.x;
    float r1 = (vals[nj*4+1]-mean)*rstd*gv.y + bv.y;
    float r2 = (vals[nj*4+2]-mean)*rstd*gv.z + bv.z;
    float r3 = (vals[nj*4+3]-mean)*rstd*gv.w + bv.w;
    if (F32OUT) {
      float4 p = { r0, r1, r2, r3 };
      *reinterpret_cast<float4*>(&outf[(size_t)m*CDIM + col]) = p;
    } else {
      uint2 p = { pk_bf16(r0, r1), pk_bf16(r2, r3) };
      *reinterpret_cast<uint2*>(outb + (size_t)m*CDIM + col) = p;
    }
  }
}

// ---------------------------------------------------------------------------
extern "C" void kernel_launch(void* const* d_in, const int* in_sizes, int n_in,
                              void* d_out, int out_size, void* d_ws, size_t ws_size,
                              hipStream_t stream)
{
  const float* pillar = (const float*)d_in[0];
  const float* w_qkv  = (const float*)d_in[2];
  const float* b_qkv  = (const float*)d_in[3];
  const float* w_out  = (const float*)d_in[4];
  const float* b_out  = (const float*)d_in[5];
  const float* ln1_g  = (const float*)d_in[6];
  const float* ln1_b  = (const float*)d_in[7];
  const float* w1     = (const float*)d_in[8];
  const float* b1     = (const float*)d_in[9];
  const float* w2     = (const float*)d_in[10];
  const float* b2     = (const float*)d_in[11];
  const float* ln2_g  = (const float*)d_in[12];
  const float* ln2_b  = (const float*)d_in[13];
  float* out = (float*)d_out;
  short* sb  = (short*)d_ws;

  short* pb    = sb;                 // pillar bf16      [8192,256]
  short* wqb   = sb + 2097152;       // w_qkv bf16       [768,256]
  short* wob   = sb + 2293760;       // w_out bf16       [256,256]
  short* w1b   = sb + 2359296;       // w1 bf16          [512,256]
  short* w2b   = sb + 2490368;       // w2 bf16          [256,512]
  short* qk    = sb + 2621440;       // Q,K bf16         [8192,512]   (dead after attn)
  short* vtg   = sb + 6815744;       // V^T bf16         [32,32,2048] (dead after attn)
  short* attnb = sb + 8912896;       // attn out bf16    [8192,256]   (dead after projln)
  short* x1b   = sb + 2621440;       // x1 bf16, aliases dead qk
  short* yhidb = sb + 4718592;       // ffn hidden bf16, aliases dead qk-tail/vtg

  // 1) all casts in one launch
  cast_all_k<<<2560, 256, 0, stream>>>(pillar, pb, w_qkv, wqb, w_out, wob,
                                       w1, w1b, w2, w2b);

  // 2) QKV projection (128x64 tiles, 768 blocks): QK -> qk; V -> vtg
  gemm128_k<CDIM, true, false, true><<<dim3(MROWS/128, QKVN/64), 512, 0, stream>>>(
      pb, wqb, b_qkv, qk, vtg, 512);

  // 3) attention -> bf16 (v11: single-pass merge)
  attn_mfma_k<<<dim3(SEQ/128, BATCH*HEADS), 512, 0, stream>>>(qk, vtg, attnb);

  // 4) out-projection + residual(pillar bf16) + LN1 -> x1b bf16 (512 blocks)
  gemmln_k<CDIM, false><<<dim3(MROWS/16), 512, 0, stream>>>(
      attnb, wob, b_out, pb, ln1_g, ln1_b, nullptr, x1b);

  // 5) FFN1 + GELU -> bf16 (128x64 tiles, 512 blocks)
  gemm128_k<CDIM, true, true, false><<<dim3(MROWS/128, FDIM/64), 512, 0, stream>>>(
      x1b, w1b, b1, yhidb, nullptr, FDIM);

  // 6) FFN2 + residual(x1 bf16) + LN2 -> out fp32 (512 blocks)
  gemmln_k<FDIM, true><<<dim3(MROWS/16), 512, 0, stream>>>(
      yhidb, w2b, b2, x1b, ln2_g, ln2_b, out, nullptr);
}

// Round 27
// 72.178 us; speedup vs baseline: 1.0042x; 1.0042x over previous
//
#include <hip/hip_runtime.h>
#include <math.h>

// Problem constants
#define MROWS 8192   // B*S
#define BATCH 4
#define SEQ   2048
#define CDIM  256
#define HEADS 8
#define DHEAD 32
#define FDIM  512
#define QKVN  768    // 3*C

typedef __attribute__((ext_vector_type(8))) short bf16x8;
typedef __attribute__((ext_vector_type(4))) float f32x4;

__device__ __forceinline__ unsigned pk_bf16(float a, float b) {
  unsigned r;
  asm("v_cvt_pk_bf16_f32 %0, %1, %2" : "=v"(r) : "v"(a), "v"(b));
  return r;
}
__device__ __forceinline__ float bf2f(short s) {
  unsigned u = ((unsigned)(unsigned short)s) << 16;
  return __builtin_bit_cast(float, u);
}
__device__ __forceinline__ float bflo(unsigned w) {
  return __builtin_bit_cast(float, w << 16);
}
__device__ __forceinline__ float bfhi(unsigned w) {
  return __builtin_bit_cast(float, w & 0xffff0000u);
}
__device__ __forceinline__ short f2bf(float f) {
  unsigned u = __builtin_bit_cast(unsigned, f);
  u = (u + 0x7FFFu + ((u >> 16) & 1u)) >> 16;   // RNE
  return (short)u;
}
__device__ __forceinline__ float fexp2(float x) {
#if __has_builtin(__builtin_amdgcn_exp2f)
  return __builtin_amdgcn_exp2f(x);
#else
  return exp2f(x);
#endif
}
__device__ __forceinline__ void gl16(const void* g, void* l) {
  __builtin_amdgcn_global_load_lds(
      (const __attribute__((address_space(1))) void*)g,
      (__attribute__((address_space(3))) void*)l, 16, 0, 0);
}
__device__ __forceinline__ float gelu_tanh(float v) {
  const float u = v * (0.7978845608f + 0.0356774081f * v * v);
  const float t = fexp2(u * 2.885390082f);   // e^{2u}
  return v * t / (t + 1.0f);                 // 0.5v(1+tanh u)
}

// ---------------------------------------------------------------------------
// Fused fp32 -> bf16 casts: pillar + 4 weight tensors, exact block ranges.
// ---------------------------------------------------------------------------
__global__ __launch_bounds__(256) void cast_all_k(
    const float* __restrict__ pillar, short* __restrict__ pb,
    const float* __restrict__ wq, short* __restrict__ wqb,
    const float* __restrict__ wo, short* __restrict__ wob,
    const float* __restrict__ w1, short* __restrict__ w1b,
    const float* __restrict__ w2, short* __restrict__ w2b)
{
  const int i = blockIdx.x * 256 + threadIdx.x;
  const float* s; short* d; int off;
  if (i < 524288)      { s = pillar; d = pb;  off = i; }
  else if (i < 573440) { s = wq;     d = wqb; off = i - 524288; }
  else if (i < 589824) { s = wo;     d = wob; off = i - 573440; }
  else if (i < 622592) { s = w1;     d = w1b; off = i - 589824; }
  else                 { s = w2;     d = w2b; off = i - 622592; }
  float4 v = reinterpret_cast<const float4*>(s)[off];
  uint2 o = { pk_bf16(v.x, v.y), pk_bf16(v.z, v.w) };
  *reinterpret_cast<uint2*>(d + off*4) = o;
}

// ---------------------------------------------------------------------------
// bf16 MFMA GEMM, 128x64 tile, BK=64, 512 threads (8 waves as 4m x 2n of
// 32x32 quadrants). gl16 staging (3 per thread), XOR-pre-swizzled source,
// linear LDS, double-buffered. Swapped MFMA: lane = m, regs = 4 consecutive
// n. NS = output row stride. VOUT: blocks with n0>=512 write the V-third of
// QKV transposed to vt[(b*8+h)*32+dv][s] (bf16) for gl16-direct V staging.
// ---------------------------------------------------------------------------
template<int K, bool BF16OUT, bool GELU, bool VOUT>
__global__ __launch_bounds__(512, 4) void gemm128_k(
    const short* __restrict__ A, const short* __restrict__ W,
    const float* __restrict__ bias, void* __restrict__ out,
    short* __restrict__ vt, int NS)
{
  __shared__ short AS[2][8192];   // [128][64] linear, swizzled content
  __shared__ short WS[2][4096];   // [64][64]
  const int tid = threadIdx.x;
  const int l   = tid & 63;
  const int w   = tid >> 6;       // 0..7
  const int m0 = blockIdx.x * 128;
  const int n0 = blockIdx.y * 64;
  const int wr = (w >> 1) * 32;   // 0,32,64,96
  const int wc = (w & 1) * 32;    // 0,32
  const int lr = l & 15;
  const int lg = l >> 4;

  f32x4 acc[2][2];
#pragma unroll
  for (int i = 0; i < 2; ++i)
#pragma unroll
    for (int j = 0; j < 2; ++j) acc[i][j] = (f32x4){0.f,0.f,0.f,0.f};

  auto stage = [&](int buf, int k0) {
#pragma unroll
    for (int i = 0; i < 2; ++i) {         // A: 1024 chunks, 2 per thread
      const int c = i*512 + tid;
      const int r = c >> 3;
      const int s = (c & 7) ^ (r & 7);    // pre-swizzled source chunk
      gl16(A + (size_t)(m0 + r)*K + k0 + s*8, &AS[buf][c*8]);
    }
    {                                      // W: 512 chunks, 1 per thread
      const int c = tid;
      const int r = c >> 3;
      const int s = (c & 7) ^ (r & 7);
      gl16(W + (size_t)(n0 + r)*K + k0 + s*8, &WS[buf][c*8]);
    }
  };

  stage(0, 0);
  const int NST = K / 64;
  for (int t = 0; t < NST; ++t) {
    const int buf = t & 1;
    __syncthreads();
    if (t + 1 < NST) stage(buf ^ 1, (t+1)*64);
#pragma unroll
    for (int ks = 0; ks < 2; ++ks) {
      const int sl = ((ks*4 + lg) ^ (lr & 7)) << 3;
      bf16x8 a[2], b[2];
#pragma unroll
      for (int mi = 0; mi < 2; ++mi)
        a[mi] = *reinterpret_cast<const bf16x8*>(&AS[buf][(wr + mi*16 + lr)*64 + sl]);
#pragma unroll
      for (int nj = 0; nj < 2; ++nj)
        b[nj] = *reinterpret_cast<const bf16x8*>(&WS[buf][(wc + nj*16 + lr)*64 + sl]);
#pragma unroll
      for (int mi = 0; mi < 2; ++mi)
#pragma unroll
        for (int nj = 0; nj < 2; ++nj)
          acc[mi][nj] = __builtin_amdgcn_mfma_f32_16x16x32_bf16(b[nj], a[mi], acc[mi][nj], 0, 0, 0);
    }
  }

#pragma unroll
  for (int mi = 0; mi < 2; ++mi) {
    const size_t m = m0 + wr + mi*16 + lr;
#pragma unroll
    for (int nj = 0; nj < 2; ++nj) {
      const int nf = n0 + wc + nj*16 + lg*4;    // full logical column
      float4 bs = *reinterpret_cast<const float4*>(&bias[nf]);
      f32x4 v = acc[mi][nj];
      float v0 = v[0]+bs.x, v1 = v[1]+bs.y, v2 = v[2]+bs.z, v3 = v[3]+bs.w;
      if (GELU) { v0 = gelu_tanh(v0); v1 = gelu_tanh(v1); v2 = gelu_tanh(v2); v3 = gelu_tanh(v3); }
      if (VOUT && n0 >= 512) {
        // V-third -> transposed vt[(b*8+h)*32+dv][s]
        const int nl = nf - 512;
        const int hh = nl >> 5, dvb = nl & 31;
        const int bb = (int)(m >> 11), ss = (int)(m & 2047);
        short* vp = vt + ((size_t)((bb*8 + hh)*32 + dvb))*2048 + ss;
        vp[0] = f2bf(v0); vp[2048] = f2bf(v1); vp[4096] = f2bf(v2); vp[6144] = f2bf(v3);
      } else if (BF16OUT) {
        uint2 p = { pk_bf16(v0, v1), pk_bf16(v2, v3) };
        *reinterpret_cast<uint2*>((short*)out + m*NS + nf) = p;
      } else {
        float4 p = { v0, v1, v2, v3 };
        *reinterpret_cast<float4*>((float*)out + m*NS + nf) = p;
      }
    }
  }
}

// ---------------------------------------------------------------------------
// MFMA flash attention v11: 2 Q-frags/wave, key-split 8 waves, 3-deep
// counted-vmcnt gl16 pipeline, setprio around compute, single-pass merge.
// ---------------------------------------------------------------------------
__global__ __launch_bounds__(512, 4) void attn_mfma_k(
    const short* __restrict__ qk, const short* __restrict__ vtg,
    short* __restrict__ attno)
{
  __shared__ short KS[2][3][2048];   // [stream][buf] 64 perm key rows x 32 d
  __shared__ short VS[2][3][2048];   // [stream][buf] 32 dv x 64 keys

  const int tid  = threadIdx.x;
  const int lane = tid & 63;
  const int wv   = tid >> 6;       // 0..7
  const int st   = wv >> 2;        // key stream 0/1
  const int qw   = wv & 3;         // q subtile (32 rows)
  const int bh   = blockIdx.y;
  const int b    = bh >> 3, h = bh & 7;
  const int q0   = blockIdx.x * 128 + qw * 32;

  const int lr = lane & 15;
  const int lg = lane >> 4;

  // Two Q fragments prescaled by 1/sqrt(D) * log2(e)  (qk row stride 512)
  bf16x8 qfa, qfb;
  {
    const float c = 0.25508134f;
    bf16x8 ra = *reinterpret_cast<const bf16x8*>(
        qk + (size_t)(b*SEQ + q0 + lr)*512 + h*DHEAD + lg*8);
    bf16x8 rb = *reinterpret_cast<const bf16x8*>(
        qk + (size_t)(b*SEQ + q0 + 16 + lr)*512 + h*DHEAD + lg*8);
#pragma unroll
    for (int j = 0; j < 8; ++j) {
      qfa[j] = f2bf(bf2f(ra[j]) * c);
      qfb[j] = f2bf(bf2f(rb[j]) * c);
    }
  }
  bf16x8 ones;
#pragma unroll
  for (int j = 0; j < 8; ++j) ones[j] = (short)0x3F80;  // bf16 1.0

  f32x4 oa0 = {0.f,0.f,0.f,0.f}, oa1 = {0.f,0.f,0.f,0.f};
  f32x4 ob0 = {0.f,0.f,0.f,0.f}, ob1 = {0.f,0.f,0.f,0.f};
  f32x4 la  = {0.f,0.f,0.f,0.f}, lb  = {0.f,0.f,0.f,0.f};

  // --- staging source precompute (per stream-thread; 1 K + 1 V chunk) ---
  const int t256 = tid & 255;
  const short* kSrc;
  {
    const int r = t256 >> 2, s = t256 & 3;
    const int rr = r & 31;
    const int key = ((rr >> 2) & 3)*8 + ((rr >> 4) & 1)*4 + (rr & 3) + (r & 32);
    const int slog = s ^ ((r >> 1) & 3);
    kSrc = qk + (size_t)(b*SEQ + st*1024 + key)*512 + 256 + h*DHEAD + slog*8;
  }
  const short* vSrc;
  {
    const int r = t256 >> 3, s = t256 & 7;
    const int slog = s ^ (r & 7);
    vSrc = vtg + ((size_t)(bh*32 + r))*2048 + st*1024 + slog*8;
  }

  // prologue: issue tiles 0 and 1 (2 gl16 per thread per tile)
  gl16(kSrc, &KS[st][0][t256*8]);
  gl16(vSrc, &VS[st][0][t256*8]);
  kSrc += 64*512; vSrc += 64;
  gl16(kSrc, &KS[st][1][t256*8]);
  gl16(vSrc, &VS[st][1][t256*8]);
  kSrc += 64*512; vSrc += 64;

  const int kxor = (lr >> 1) & 3;
  const int vxor = lr & 7;

  int buf = 0, nbuf = 2;           // buf = t%3 ; nbuf = (t+2)%3
  for (int t = 0; t < 16; ++t) {
    // own tile-t loads landed (in-order vmcnt: <=2 outstanding = t+1's)
    if (t < 15) asm volatile("s_waitcnt vmcnt(2)" ::: "memory");
    else        asm volatile("s_waitcnt vmcnt(0)" ::: "memory");
    __builtin_amdgcn_s_barrier();    // all waves' t-loads landed
    asm volatile("" ::: "memory");   // compiler fence (no LDS-read hoisting)

    if (t + 2 < 16) {                // overwrite buf (t-1)%3: reads done
      gl16(kSrc, &KS[st][nbuf][t256*8]);
      gl16(vSrc, &VS[st][nbuf][t256*8]);
      kSrc += 64*512; vSrc += 64;
    }

    __builtin_amdgcn_s_setprio(1);   // T5: favor compute-phase waves

#pragma unroll
    for (int half = 0; half < 2; ++half) {
      const int krow = (half*32 + lr)*32 + ((lg ^ kxor) << 3);
      bf16x8 kf0 = *reinterpret_cast<const bf16x8*>(&KS[st][buf][krow]);
      bf16x8 kf1 = *reinterpret_cast<const bf16x8*>(&KS[st][buf][krow + 512]);
      const int vcol = (((half*4 + lg) ^ vxor) << 3);
      bf16x8 vf0 = *reinterpret_cast<const bf16x8*>(&VS[st][buf][lr*64 + vcol]);
      bf16x8 vf1 = *reinterpret_cast<const bf16x8*>(&VS[st][buf][(lr+16)*64 + vcol]);
      f32x4 z = {0.f,0.f,0.f,0.f};

      // frag A (q rows q0+lr)
      {
        f32x4 s0 = __builtin_amdgcn_mfma_f32_16x16x32_bf16(kf0, qfa, z, 0, 0, 0);
        f32x4 s1 = __builtin_amdgcn_mfma_f32_16x16x32_bf16(kf1, qfa, z, 0, 0, 0);
        float p0 = fexp2(s0[0]), p1 = fexp2(s0[1]), p2 = fexp2(s0[2]), p3 = fexp2(s0[3]);
        float p4 = fexp2(s1[0]), p5 = fexp2(s1[1]), p6 = fexp2(s1[2]), p7 = fexp2(s1[3]);
        union { bf16x8 v; unsigned w[4]; } pfu;
        pfu.w[0] = pk_bf16(p0, p1); pfu.w[1] = pk_bf16(p2, p3);
        pfu.w[2] = pk_bf16(p4, p5); pfu.w[3] = pk_bf16(p6, p7);
        oa0 = __builtin_amdgcn_mfma_f32_16x16x32_bf16(vf0, pfu.v, oa0, 0, 0, 0);
        oa1 = __builtin_amdgcn_mfma_f32_16x16x32_bf16(vf1, pfu.v, oa1, 0, 0, 0);
        la  = __builtin_amdgcn_mfma_f32_16x16x32_bf16(ones, pfu.v, la, 0, 0, 0);
      }
      // frag B (q rows q0+16+lr)
      {
        f32x4 s0 = __builtin_amdgcn_mfma_f32_16x16x32_bf16(kf0, qfb, z, 0, 0, 0);
        f32x4 s1 = __builtin_amdgcn_mfma_f32_16x16x32_bf16(kf1, qfb, z, 0, 0, 0);
        float p0 = fexp2(s0[0]), p1 = fexp2(s0[1]), p2 = fexp2(s0[2]), p3 = fexp2(s0[3]);
        float p4 = fexp2(s1[0]), p5 = fexp2(s1[1]), p6 = fexp2(s1[2]), p7 = fexp2(s1[3]);
        union { bf16x8 v; unsigned w[4]; } pfu;
        pfu.w[0] = pk_bf16(p0, p1); pfu.w[1] = pk_bf16(p2, p3);
        pfu.w[2] = pk_bf16(p4, p5); pfu.w[3] = pk_bf16(p6, p7);
        ob0 = __builtin_amdgcn_mfma_f32_16x16x32_bf16(vf0, pfu.v, ob0, 0, 0, 0);
        ob1 = __builtin_amdgcn_mfma_f32_16x16x32_bf16(vf1, pfu.v, ob1, 0, 0, 0);
        lb  = __builtin_amdgcn_mfma_f32_16x16x32_bf16(ones, pfu.v, lb, 0, 0, 0);
      }
    }

    __builtin_amdgcn_s_setprio(0);

    buf = (buf == 2) ? 0 : buf + 1;
    nbuf = (nbuf == 2) ? 0 : nbuf + 1;
  }

  // single-pass merge of the two key streams: mg = [(qw*64+lane)*2+frag]*9
  // floats = 18,432B, entirely within KS (24,576B). Pure sums (max-free SM).
  float* mg = (float*)&KS[0][0][0];
  const int mia = ((qw*64 + lane)*2 + 0)*9;
  const int mib = ((qw*64 + lane)*2 + 1)*9;

  __syncthreads();                      // all tile-15 LDS reads done
  if (st == 1) {
    mg[mia+0]=oa0[0]; mg[mia+1]=oa0[1]; mg[mia+2]=oa0[2]; mg[mia+3]=oa0[3];
    mg[mia+4]=oa1[0]; mg[mia+5]=oa1[1]; mg[mia+6]=oa1[2]; mg[mia+7]=oa1[3];
    mg[mia+8]=la[0];
    mg[mib+0]=ob0[0]; mg[mib+1]=ob0[1]; mg[mib+2]=ob0[2]; mg[mib+3]=ob0[3];
    mg[mib+4]=ob1[0]; mg[mib+5]=ob1[1]; mg[mib+6]=ob1[2]; mg[mib+7]=ob1[3];
    mg[mib+8]=lb[0];
  }
  __syncthreads();
  if (st == 0) {
    {
      const float inv = 1.f / (la[0] + mg[mia+8]);
      float a0 = (oa0[0]+mg[mia+0])*inv, a1 = (oa0[1]+mg[mia+1])*inv;
      float a2 = (oa0[2]+mg[mia+2])*inv, a3 = (oa0[3]+mg[mia+3])*inv;
      float b0 = (oa1[0]+mg[mia+4])*inv, b1 = (oa1[1]+mg[mia+5])*inv;
      float b2 = (oa1[2]+mg[mia+6])*inv, b3 = (oa1[3]+mg[mia+7])*inv;
      short* op = attno + (size_t)(b*SEQ + q0 + lr)*CDIM + h*DHEAD;
      uint2 r0 = { pk_bf16(a0, a1), pk_bf16(a2, a3) };
      uint2 r1 = { pk_bf16(b0, b1), pk_bf16(b2, b3) };
      *reinterpret_cast<uint2*>(op + lg*4)      = r0;
      *reinterpret_cast<uint2*>(op + 16 + lg*4) = r1;
    }
    {
      const float inv = 1.f / (lb[0] + mg[mib+8]);
      float a0 = (ob0[0]+mg[mib+0])*inv, a1 = (ob0[1]+mg[mib+1])*inv;
      float a2 = (ob0[2]+mg[mib+2])*inv, a3 = (ob0[3]+mg[mib+3])*inv;
      float b0 = (ob1[0]+mg[mib+4])*inv, b1 = (ob1[1]+mg[mib+5])*inv;
      float b2 = (ob1[2]+mg[mib+6])*inv, b3 = (ob1[3]+mg[mib+7])*inv;
      short* op = attno + (size_t)(b*SEQ + q0 + 16 + lr)*CDIM + h*DHEAD;
      uint2 r0 = { pk_bf16(a0, a1), pk_bf16(a2, a3) };
      uint2 r1 = { pk_bf16(b0, b1), pk_bf16(b2, b3) };
      *reinterpret_cast<uint2*>(op + lg*4)      = r0;
      *reinterpret_cast<uint2*>(op + 16 + lg*4) = r1;
    }
  }
}

// ---------------------------------------------------------------------------
// Fused GEMM(N=256) + residual + LayerNorm, 16-row x 256-col tile per block
// (512 blocks = 2 blocks/CU for barrier-drain overlap). 8 waves, each owns
// 32 cols (2 n-frags); same gl16+swizzle dbuf staging skeleton as gemm128_k.
// Epilogue: residual add (bf16), row-reduce via shfl_xor over lg + LDS
// partials over the 8 waves, normalize, write bf16 or fp32.
// ---------------------------------------------------------------------------
template<int K, bool F32OUT>
__global__ __launch_bounds__(512, 4) void gemmln_k(
    const short* __restrict__ A, const short* __restrict__ W,
    const float* __restrict__ bias, const short* __restrict__ resid,
    const float* __restrict__ g, const float* __restrict__ bta,
    float* __restrict__ outf, short* __restrict__ outb)
{
  __shared__ short AS[2][1024];    // [16][64]
  __shared__ short WS[2][16384];   // [256][64]
  __shared__ float P[16][8][2];    // per-(row, wave) partial sum/sumsq
  const int tid = threadIdx.x;
  const int l   = tid & 63;
  const int wv  = tid >> 6;        // 0..7: cols wv*32..+31
  const int m0  = blockIdx.x * 16;
  const int lr  = l & 15;
  const int lg  = l >> 4;

  f32x4 acc[2];
#pragma unroll
  for (int j = 0; j < 2; ++j) acc[j] = (f32x4){0.f,0.f,0.f,0.f};

  auto stage = [&](int buf, int k0) {
    if (tid < 128) {                     // A: 16 rows x 8 chunks
      const int r = tid >> 3;
      const int s = (tid & 7) ^ (r & 7);
      gl16(A + (size_t)(m0 + r)*K + k0 + s*8, &AS[buf][tid*8]);
    }
#pragma unroll
    for (int i = 0; i < 4; ++i) {        // W: 256 rows x 8 chunks = 2048
      const int c = i*512 + tid;
      const int r = c >> 3;
      const int s = (c & 7) ^ (r & 7);
      gl16(W + (size_t)r*K + k0 + s*8, &WS[buf][c*8]);
    }
  };

  stage(0, 0);
  const int NST = K / 64;
  for (int t = 0; t < NST; ++t) {
    const int buf = t & 1;
    __syncthreads();
    if (t + 1 < NST) stage(buf ^ 1, (t+1)*64);
#pragma unroll
    for (int ks = 0; ks < 2; ++ks) {
      const int sl = ((ks*4 + lg) ^ (lr & 7)) << 3;
      bf16x8 a = *reinterpret_cast<const bf16x8*>(&AS[buf][lr*64 + sl]);
#pragma unroll
      for (int nj = 0; nj < 2; ++nj) {
        bf16x8 b = *reinterpret_cast<const bf16x8*>(&WS[buf][(wv*32 + nj*16 + lr)*64 + sl]);
        acc[nj] = __builtin_amdgcn_mfma_f32_16x16x32_bf16(b, a, acc[nj], 0, 0, 0);
      }
    }
  }

  // epilogue: bias + residual, row stats, LN
  const int m = m0 + lr;
  float vals[8];
  float s = 0.f, sq = 0.f;
#pragma unroll
  for (int nj = 0; nj < 2; ++nj) {
    const int col = wv*32 + nj*16 + lg*4;
    float4 bs = *reinterpret_cast<const float4*>(&bias[col]);
    uint2 rv = *reinterpret_cast<const uint2*>(&resid[(size_t)m*CDIM + col]);
    float v0 = acc[nj][0] + bs.x + bflo(rv.x);
    float v1 = acc[nj][1] + bs.y + bfhi(rv.x);
    float v2 = acc[nj][2] + bs.z + bflo(rv.y);
    float v3 = acc[nj][3] + bs.w + bfhi(rv.y);
    vals[nj*4+0]=v0; vals[nj*4+1]=v1; vals[nj*4+2]=v2; vals[nj*4+3]=v3;
    s += (v0+v1)+(v2+v3);
    sq += (v0*v0+v1*v1)+(v2*v2+v3*v3);
  }
  // reduce across the 4 lg-lanes (same row, 32 cols of this wave)
  s  += __shfl_xor(s, 16);  s  += __shfl_xor(s, 32);
  sq += __shfl_xor(sq, 16); sq += __shfl_xor(sq, 32);
  if (lg == 0) { P[lr][wv][0] = s; P[lr][wv][1] = sq; }
  __syncthreads();
  float S = 0.f, SQ = 0.f;
#pragma unroll
  for (int w8 = 0; w8 < 8; ++w8) { S += P[lr][w8][0]; SQ += P[lr][w8][1]; }
  const float mean = S * (1.f/CDIM);
  const float var  = SQ * (1.f/CDIM) - mean*mean;
  const float rstd = rsqrtf(var + 1e-5f);
#pragma unroll
  for (int nj = 0; nj < 2; ++nj) {
    const int col = wv*32 + nj*16 + lg*4;
    float4 gv = *reinterpret_cast<const float4*>(&g[col]);
    float4 bv = *reinterpret_cast<const float4*>(&bta[col]);
    float r0 = (vals[nj*4+0]-mean)*rstd*gv.x + bv.x;
    float r1 = (vals[nj*4+1]-mean)*rstd*gv.y + bv.y;
    float r2 = (vals[nj*4+2]-mean)*rstd*gv.z + bv.z;
    float r3 = (vals[nj*4+3]-mean)*rstd*gv.w + bv.w;
    if (F32OUT) {
      float4 p = { r0, r1, r2, r3 };
      *reinterpret_cast<float4*>(&outf[(size_t)m*CDIM + col]) = p;
    } else {
      uint2 p = { pk_bf16(r0, r1), pk_bf16(r2, r3) };
      *reinterpret_cast<uint2*>(outb + (size_t)m*CDIM + col) = p;
    }
  }
}

// ---------------------------------------------------------------------------
extern "C" void kernel_launch(void* const* d_in, const int* in_sizes, int n_in,
                              void* d_out, int out_size, void* d_ws, size_t ws_size,
                              hipStream_t stream)
{
  const float* pillar = (const float*)d_in[0];
  const float* w_qkv  = (const float*)d_in[2];
  const float* b_qkv  = (const float*)d_in[3];
  const float* w_out  = (const float*)d_in[4];
  const float* b_out  = (const float*)d_in[5];
  const float* ln1_g  = (const float*)d_in[6];
  const float* ln1_b  = (const float*)d_in[7];
  const float* w1     = (const float*)d_in[8];
  const float* b1     = (const float*)d_in[9];
  const float* w2     = (const float*)d_in[10];
  const float* b2     = (const float*)d_in[11];
  const float* ln2_g  = (const float*)d_in[12];
  const float* ln2_b  = (const float*)d_in[13];
  float* out = (float*)d_out;
  short* sb  = (short*)d_ws;

  short* pb    = sb;                 // pillar bf16      [8192,256]
  short* wqb   = sb + 2097152;       // w_qkv bf16       [768,256]
  short* wob   = sb + 2293760;       // w_out bf16       [256,256]
  short* w1b   = sb + 2359296;       // w1 bf16          [512,256]
  short* w2b   = sb + 2490368;       // w2 bf16          [256,512]
  short* qk    = sb + 2621440;       // Q,K bf16         [8192,512]   (dead after attn)
  short* vtg   = sb + 6815744;       // V^T bf16         [32,32,2048] (dead after attn)
  short* attnb = sb + 8912896;       // attn out bf16    [8192,256]   (dead after projln)
  short* x1b   = sb + 2621440;       // x1 bf16, aliases dead qk
  short* yhidb = sb + 4718592;       // ffn hidden bf16, aliases dead qk-tail/vtg

  // 1) all casts in one launch
  cast_all_k<<<2560, 256, 0, stream>>>(pillar, pb, w_qkv, wqb, w_out, wob,
                                       w1, w1b, w2, w2b);

  // 2) QKV projection (128x64 tiles, 768 blocks): QK -> qk; V -> vtg
  gemm128_k<CDIM, true, false, true><<<dim3(MROWS/128, QKVN/64), 512, 0, stream>>>(
      pb, wqb, b_qkv, qk, vtg, 512);

  // 3) attention -> bf16 (v11: single-pass merge)
  attn_mfma_k<<<dim3(SEQ/128, BATCH*HEADS), 512, 0, stream>>>(qk, vtg, attnb);

  // 4) out-projection + residual(pillar bf16) + LN1 -> x1b bf16 (512 blocks)
  gemmln_k<CDIM, false><<<dim3(MROWS/16), 512, 0, stream>>>(
      attnb, wob, b_out, pb, ln1_g, ln1_b, nullptr, x1b);

  // 5) FFN1 + GELU -> bf16 (128x64 tiles, 512 blocks)
  gemm128_k<CDIM, true, true, false><<<dim3(MROWS/128, FDIM/64), 512, 0, stream>>>(
      x1b, w1b, b1, yhidb, nullptr, FDIM);

  // 6) FFN2 + residual(x1 bf16) + LN2 -> out fp32 (512 blocks)
  gemmln_k<FDIM, true><<<dim3(MROWS/16), 512, 0, stream>>>(
      yhidb, w2b, b2, x1b, ln2_g, ln2_b, out, nullptr);
}